// Round 6
// baseline (10.218 us; speedup 1.0000x reference)
//
#include <hip/hip_runtime.h>
#include <math.h>

// GNN_59219009077824  — B=1024, N=256, F=6, H=128, O=64
//
// Low-rank structure: edge(i,j) = cond_i | cond_j among valid nodes.
// C = valid & cond, NC = valid & !cond.
//   dinv = a = nv^-0.5 for C;  dinv = c = (nc+1)^-0.5 for NC.
// (An Y)_i = a*S_all for i in C;  c*S_c + c^2*Y_i for i in NC.
// Pooled output closed-form:
//   out[o] = (alpha*y2C[o] + beta*y2N[o])/nv + b2[o],
//   alpha = a*nc*(nc*a + (nv-nc)*c), beta = c*(nc*a + c)
//   -> single fused matvec over g[h] = (alpha*hC[h] + beta*hN[h])/nv.
// R1: LDS atomics -> ballot/shuffle (20.0 -> 13.6 us).
// R2-4: DPP wave reduction + weight prefetch (13.6 -> 11.8 us).
// R5: one wave per batch (11.8 -> 9.9 us).
// R6: ZERO LDS/barrier — layer-2 via v_readlane broadcast; fused single
//     matvec; float4 x-loads (6 instead of 12 VMEM); counts from ballots.

#define NB 1024
#define NN 256
#define NF 6
#define NH 128
#define NO 64

// v_add_f32 with DPP-moved operand; old=0 so masked-off lanes add 0.
template <int CTRL, int ROW_MASK, int BANK_MASK>
__device__ __forceinline__ float dpp_add(float v) {
    int moved = __builtin_amdgcn_update_dpp(0, __float_as_int(v),
                                            CTRL, ROW_MASK, BANK_MASK, true);
    return v + __int_as_float(moved);
}

// Full 64-lane sum; result valid in lane 63. Canonical gfx9 DPP sequence.
__device__ __forceinline__ float wave_sum64(float v) {
    v = dpp_add<0x111, 0xf, 0xf>(v); // row_shr:1
    v = dpp_add<0x112, 0xf, 0xf>(v); // row_shr:2
    v = dpp_add<0x114, 0xf, 0xe>(v); // row_shr:4
    v = dpp_add<0x118, 0xf, 0xc>(v); // row_shr:8
    v = dpp_add<0x142, 0xa, 0xf>(v); // row_bcast:15
    v = dpp_add<0x143, 0xc, 0xf>(v); // row_bcast:31
    return v;
}

__device__ __forceinline__ float bcast63(float v) {
    return __int_as_float(__builtin_amdgcn_readlane(__float_as_int(v), 63));
}

__device__ __forceinline__ float rdlane(float v, int l) {
    return __int_as_float(__builtin_amdgcn_readlane(__float_as_int(v), l));
}

__global__ __launch_bounds__(64) void gnn_kernel(
    const float* __restrict__ x,    // [B,N,F]
    const float* __restrict__ W1,   // [F,H]
    const float* __restrict__ b1,   // [H]
    const float* __restrict__ W2,   // [H,O]
    const float* __restrict__ b2,   // [O]
    float* __restrict__ out)        // [B,O]
{
    const int b    = blockIdx.x;
    const int lane = threadIdx.x;   // 0..63, one wave per batch

    // ---- Prefetch weights; latency overlaps the x loads ----
    float w1a[NF], w1b[NF];
    #pragma unroll
    for (int f = 0; f < NF; ++f) {
        w1a[f] = W1[f * NH + lane];
        w1b[f] = W1[f * NH + lane + 64];
    }
    const float b1a = b1[lane];
    const float b1b = b1[lane + 64];
    const float b2r = b2[lane];

    // ---- Load 4 consecutive nodes/lane as 6 float4s ----
    const float4* xp = (const float4*)(x + (size_t)b * NN * NF
                                         + (size_t)lane * 4 * NF);
    float4 q0 = xp[0], q1 = xp[1], q2 = xp[2], q3 = xp[3], q4 = xp[4], q5 = xp[5];
    float xf[4][NF] = {
        { q0.x, q0.y, q0.z, q0.w, q1.x, q1.y },
        { q1.z, q1.w, q2.x, q2.y, q2.z, q2.w },
        { q3.x, q3.y, q3.z, q3.w, q4.x, q4.y },
        { q4.z, q4.w, q5.x, q5.y, q5.z, q5.w },
    };

    // ---- Classify + per-lane masked accumulate; counts via ballots ----
    bool ncf[4];
    float r[12];
    #pragma unroll
    for (int j = 0; j < 12; ++j) r[j] = 0.f;
    int nv = 0, nc = 0, nnc = 0;

    #pragma unroll
    for (int k = 0; k < 4; ++k) {
        float absum = fabsf(xf[k][0]) + fabsf(xf[k][1]) + fabsf(xf[k][2])
                    + fabsf(xf[k][3]) + fabsf(xf[k][4]) + fabsf(xf[k][5]);
        const bool valid = (absum != 0.f);
        const bool condv = valid && ((xf[k][3] != 0.f) || (xf[k][4] != 0.f));
        const bool isNC  = valid && !condv;
        ncf[k] = isNC;

        nv  += (int)__popcll(__ballot(valid));
        nc  += (int)__popcll(__ballot(condv));
        nnc += (int)__popcll(__ballot(isNC));

        if (condv) {
            #pragma unroll
            for (int f = 0; f < NF; ++f) r[f] += xf[k][f];
        } else if (isNC) {
            #pragma unroll
            for (int f = 0; f < NF; ++f) r[f + 6] += xf[k][f];
        }
    }

    // ---- Wave reduction (DPP, VALU-only) + SGPR broadcast ----
    #pragma unroll
    for (int j = 0; j < 12; ++j) r[j] = wave_sum64(r[j]);
    float fs[12];
    #pragma unroll
    for (int j = 0; j < 12; ++j) fs[j] = bcast63(r[j]);

    if (nv == 0) {                  // no valid nodes: zeros
        out[(size_t)b * NO + lane] = 0.f;
        return;
    }

    const float a  = 1.f / sqrtf((float)nv);
    const float c  = 1.f / sqrtf((float)(nc + 1));
    const float c2 = c * c;

    // ---- Layer 1: lane handles channels h=lane and h=lane+64 ----
    float zc0 = 0.f, zn0 = 0.f, zc1 = 0.f, zn1 = 0.f;
    #pragma unroll
    for (int f = 0; f < NF; ++f) {
        zc0 = fmaf(fs[f],     w1a[f], zc0);
        zn0 = fmaf(fs[f + 6], w1a[f], zn0);
        zc1 = fmaf(fs[f],     w1b[f], zc1);
        zn1 = fmaf(fs[f + 6], w1b[f], zn1);
    }
    const float Sc0   = a * zc0,       Sc1   = a * zc1;
    const float Sall0 = Sc0 + c * zn0, Sall1 = Sc1 + c * zn1;

    const float hCa = fmaxf(fmaf(a, Sall0, b1a), 0.f);
    const float hCb = fmaxf(fmaf(a, Sall1, b1b), 0.f);

    // NC nodes: sum_i relu(c*Sc + c2*Z_i + b1). Empty when nnc==0 (bench case).
    float acc0 = 0.f, acc1 = 0.f;
    if (nnc > 0) {
        const float vl0 = fmaf(c, Sc0, b1a);
        const float vl1 = fmaf(c, Sc1, b1b);
        #pragma unroll
        for (int k = 0; k < 4; ++k) {
            unsigned long long m = __ballot(ncf[k]);   // wave-uniform
            while (m) {
                const int l = (int)__ffsll((long long)m) - 1;
                m &= m - 1;
                float sf[NF];
                #pragma unroll
                for (int f = 0; f < NF; ++f) sf[f] = rdlane(xf[k][f], l);
                float z0 = 0.f, z1 = 0.f;
                #pragma unroll
                for (int f = 0; f < NF; ++f) {
                    z0 = fmaf(sf[f], w1a[f], z0);
                    z1 = fmaf(sf[f], w1b[f], z1);
                }
                acc0 += fmaxf(fmaf(c2, z0, vl0), 0.f);
                acc1 += fmaxf(fmaf(c2, z1, vl1), 0.f);
            }
        }
    }

    // ---- Fold aggregation-2 + pool into one matvec over g[h] ----
    const float alpha = a * (float)nc * ((float)nc * a + (float)(nv - nc) * c);
    const float beta  = c * ((float)nc * a + c);
    const float inv_nv = 1.f / (float)nv;
    const float ga = (alpha * hCa + beta * acc0) * inv_nv;  // channel lane
    const float gb = (alpha * hCb + beta * acc1) * inv_nv;  // channel lane+64

    // y[o] = sum_h g[h] * W2[h][o]; g broadcast via readlane (uniform index)
    float y = 0.f;
    #pragma unroll
    for (int hh = 0; hh < 64; ++hh) {
        y = fmaf(rdlane(ga, hh), W2[hh * NO + lane],        y);
        y = fmaf(rdlane(gb, hh), W2[(hh + 64) * NO + lane], y);
    }

    out[(size_t)b * NO + lane] = y + b2r;
}

extern "C" void kernel_launch(void* const* d_in, const int* in_sizes, int n_in,
                              void* d_out, int out_size, void* d_ws, size_t ws_size,
                              hipStream_t stream) {
    const float* x  = (const float*)d_in[0];
    const float* W1 = (const float*)d_in[1];
    const float* b1 = (const float*)d_in[2];
    const float* W2 = (const float*)d_in[3];
    const float* b2 = (const float*)d_in[4];
    float* out = (float*)d_out;

    gnn_kernel<<<NB, 64, 0, stream>>>(x, W1, b1, W2, b2, out);
}

// Round 7
// 9.372 us; speedup vs baseline: 1.0903x; 1.0903x over previous
//
#include <hip/hip_runtime.h>
#include <math.h>

// GNN_59219009077824  — B=1024, N=256, F=6, H=128, O=64
//
// Low-rank structure: edge(i,j) = cond_i | cond_j among valid nodes.
// C = valid & cond, NC = valid & !cond.
//   dinv = a = nv^-0.5 for C;  dinv = c = (nc+1)^-0.5 for NC.
// (An Y)_i = a*S_all for i in C;  c*S_c + c^2*Y_i for i in NC.
// out[o] = (alpha*y2C[o] + beta*y2N[o])/nv + b2[o],
//   alpha = a*nc*(nc*a+(nv-nc)*c), beta = c*(nc*a+c)
//   -> single matvec over g[h] = (alpha*hC[h] + beta*hN[h])/nv.
// R1: LDS atomics -> ballot/shuffle (20.0 -> 13.6 us).
// R2-4: DPP wave reduction + weight prefetch (13.6 -> 11.8 us).
// R5: one wave per batch (11.8 -> 9.9 us).
// R6: zero-LDS readlane matvec (10.2 us — neutral; latency-bound, no TLP).
// R7: TWO waves per batch — halves every per-wave serial cost (3 x-loads,
//     1 h/lane, 64 W2 regs, 64-step matvec) and doubles waves/SIMD for
//     latency hiding. W2 prefetched to registers at entry.

#define NB 1024
#define NN 256
#define NF 6
#define NH 128
#define NO 64

// v_add_f32 with DPP-moved operand; old=0 so masked-off lanes add 0.
template <int CTRL, int ROW_MASK, int BANK_MASK>
__device__ __forceinline__ float dpp_add(float v) {
    int moved = __builtin_amdgcn_update_dpp(0, __float_as_int(v),
                                            CTRL, ROW_MASK, BANK_MASK, true);
    return v + __int_as_float(moved);
}

// Full 64-lane sum; result valid in lane 63. Canonical gfx9 DPP sequence.
__device__ __forceinline__ float wave_sum64(float v) {
    v = dpp_add<0x111, 0xf, 0xf>(v); // row_shr:1
    v = dpp_add<0x112, 0xf, 0xf>(v); // row_shr:2
    v = dpp_add<0x114, 0xf, 0xe>(v); // row_shr:4
    v = dpp_add<0x118, 0xf, 0xc>(v); // row_shr:8
    v = dpp_add<0x142, 0xa, 0xf>(v); // row_bcast:15
    v = dpp_add<0x143, 0xc, 0xf>(v); // row_bcast:31
    return v;
}

__device__ __forceinline__ float rdlane(float v, int l) {
    return __int_as_float(__builtin_amdgcn_readlane(__float_as_int(v), l));
}

__global__ __launch_bounds__(128) void gnn_kernel(
    const float* __restrict__ x,    // [B,N,F]
    const float* __restrict__ W1,   // [F,H]
    const float* __restrict__ b1,   // [H]
    const float* __restrict__ W2,   // [H,O]
    const float* __restrict__ b2,   // [O]
    float* __restrict__ out)        // [B,O]
{
    const int b    = blockIdx.x;
    const int t    = threadIdx.x;
    const int wid  = t >> 6;        // 0 or 1
    const int lane = t & 63;
    const int h    = (wid << 6) + lane;   // this thread's hidden channel

    __shared__ float  psum[2][16];   // per-wave reduced sums + counts
    __shared__ float4 xc4[NN][2];    // NC-compacted features (general case)
    __shared__ float  ypart[NO];     // wave1's partial output

    // ---- x loads first (HBM, longest latency): 2 nodes = 3 float4 ----
    const float4* xp = (const float4*)(x + (size_t)b * NN * NF
                                         + (size_t)((wid << 7) + lane * 2) * NF);
    float4 q0 = xp[0], q1 = xp[1], q2 = xp[2];
    float xf[2][NF] = {
        { q0.x, q0.y, q0.z, q0.w, q1.x, q1.y },
        { q1.z, q1.w, q2.x, q2.y, q2.z, q2.w },
    };

    // ---- Weight prefetch (L2); overlaps classify/reduce ----
    float w1r[NF];
    #pragma unroll
    for (int f = 0; f < NF; ++f) w1r[f] = W1[f * NH + h];
    const float b1r = b1[h];
    const float b2r = b2[lane];
    float w2r[64];                   // W2[h'][lane] for h' in this wave's range
    #pragma unroll
    for (int hh = 0; hh < 64; ++hh)
        w2r[hh] = W2[(size_t)(((wid << 6) + hh) * NO) + lane];

    // ---- Classify 2 nodes, per-lane masked accumulate ----
    bool ncf[2];
    unsigned long long mN0, mN1;
    float r[12];
    #pragma unroll
    for (int j = 0; j < 12; ++j) r[j] = 0.f;
    int nvw = 0, ncw = 0;

    #pragma unroll
    for (int k = 0; k < 2; ++k) {
        float absum = fabsf(xf[k][0]) + fabsf(xf[k][1]) + fabsf(xf[k][2])
                    + fabsf(xf[k][3]) + fabsf(xf[k][4]) + fabsf(xf[k][5]);
        const bool valid = (absum != 0.f);
        const bool condv = valid && ((xf[k][3] != 0.f) || (xf[k][4] != 0.f));
        const bool isNC  = valid && !condv;
        ncf[k] = isNC;

        nvw += (int)__popcll(__ballot(valid));
        ncw += (int)__popcll(__ballot(condv));
        if (k == 0) mN0 = __ballot(isNC); else mN1 = __ballot(isNC);

        if (condv) {
            #pragma unroll
            for (int f = 0; f < NF; ++f) r[f] += xf[k][f];
        } else if (isNC) {
            #pragma unroll
            for (int f = 0; f < NF; ++f) r[f + 6] += xf[k][f];
        }
    }
    const int c0   = (int)__popcll(mN0);
    const int nncw = c0 + (int)__popcll(mN1);

    // ---- DPP wave reduction; lane 63 posts per-wave results ----
    #pragma unroll
    for (int j = 0; j < 12; ++j) r[j] = wave_sum64(r[j]);
    if (lane == 63) {
        #pragma unroll
        for (int j = 0; j < 12; ++j) psum[wid][j] = r[j];
        psum[wid][12] = (float)nvw;
        psum[wid][13] = (float)ncw;
        psum[wid][14] = (float)nncw;
    }

    // ---- NC compaction: wave0 fills upward, wave1 downward (order-free) ----
    const unsigned long long ltm = (1ull << lane) - 1ull;
    if (ncf[0]) {
        const int rank = (int)__popcll(mN0 & ltm);
        const int idx  = wid ? (NN - 1 - rank) : rank;
        xc4[idx][0] = make_float4(xf[0][0], xf[0][1], xf[0][2], xf[0][3]);
        xc4[idx][1] = make_float4(xf[0][4], xf[0][5], 0.f, 0.f);
    }
    if (ncf[1]) {
        const int rank = c0 + (int)__popcll(mN1 & ltm);
        const int idx  = wid ? (NN - 1 - rank) : rank;
        xc4[idx][0] = make_float4(xf[1][0], xf[1][1], xf[1][2], xf[1][3]);
        xc4[idx][1] = make_float4(xf[1][4], xf[1][5], 0.f, 0.f);
    }
    __syncthreads();

    // ---- Combine the two waves' partials (broadcast LDS reads) ----
    float fs[12];
    #pragma unroll
    for (int j = 0; j < 12; ++j) fs[j] = psum[0][j] + psum[1][j];
    const int nv   = (int)(psum[0][12] + psum[1][12]);
    const int nc   = (int)(psum[0][13] + psum[1][13]);
    const int nnc0 = (int)psum[0][14];
    const int nnc1 = (int)psum[1][14];

    if (nv == 0) {                  // block-uniform; no barrier crossed after
        if (wid == 0) out[(size_t)b * NO + lane] = 0.f;
        return;
    }

    const float a  = 1.f / sqrtf((float)nv);
    const float c  = 1.f / sqrtf((float)(nc + 1));
    const float c2 = c * c;

    // ---- Layer 1 for channel h ----
    float zc = 0.f, zn = 0.f;
    #pragma unroll
    for (int f = 0; f < NF; ++f) {
        zc = fmaf(fs[f],     w1r[f], zc);
        zn = fmaf(fs[f + 6], w1r[f], zn);
    }
    const float Sc   = a * zc;
    const float Sall = Sc + c * zn;
    const float hC   = fmaxf(fmaf(a, Sall, b1r), 0.f);

    float acc = 0.f;                 // sum over NC nodes (empty in bench case)
    if (nnc0 + nnc1 > 0) {
        const float vloc = fmaf(c, Sc, b1r);
        for (int k = 0; k < nnc0; ++k) {
            const float4 u0 = xc4[k][0];
            const float4 u1 = xc4[k][1];
            float z = u0.x * w1r[0];
            z = fmaf(u0.y, w1r[1], z);
            z = fmaf(u0.z, w1r[2], z);
            z = fmaf(u0.w, w1r[3], z);
            z = fmaf(u1.x, w1r[4], z);
            z = fmaf(u1.y, w1r[5], z);
            acc += fmaxf(fmaf(c2, z, vloc), 0.f);
        }
        for (int k = NN - nnc1; k < NN; ++k) {
            const float4 u0 = xc4[k][0];
            const float4 u1 = xc4[k][1];
            float z = u0.x * w1r[0];
            z = fmaf(u0.y, w1r[1], z);
            z = fmaf(u0.z, w1r[2], z);
            z = fmaf(u0.w, w1r[3], z);
            z = fmaf(u1.x, w1r[4], z);
            z = fmaf(u1.y, w1r[5], z);
            acc += fmaxf(fmaf(c2, z, vloc), 0.f);
        }
    }

    // ---- Fold aggregation-2 + pool: g per channel, then partial matvec ----
    const float alpha  = a * (float)nc * ((float)nc * a + (float)(nv - nc) * c);
    const float beta   = c * ((float)nc * a + c);
    const float inv_nv = 1.f / (float)nv;
    const float g = (alpha * hC + beta * acc) * inv_nv;

    // partial y over this wave's 64 channels; 2 chains to break FMA latency
    float y0 = 0.f, y1 = 0.f;
    #pragma unroll
    for (int hh = 0; hh < 64; hh += 2) {
        y0 = fmaf(rdlane(g, hh),     w2r[hh],     y0);
        y1 = fmaf(rdlane(g, hh + 1), w2r[hh + 1], y1);
    }
    const float y = y0 + y1;

    if (wid == 1) ypart[lane] = y;
    __syncthreads();
    if (wid == 0) out[(size_t)b * NO + lane] = y + ypart[lane] + b2r;
}

extern "C" void kernel_launch(void* const* d_in, const int* in_sizes, int n_in,
                              void* d_out, int out_size, void* d_ws, size_t ws_size,
                              hipStream_t stream) {
    const float* x  = (const float*)d_in[0];
    const float* W1 = (const float*)d_in[1];
    const float* b1 = (const float*)d_in[2];
    const float* W2 = (const float*)d_in[3];
    const float* b2 = (const float*)d_in[4];
    float* out = (float*)d_out;

    gnn_kernel<<<NB, 128, 0, stream>>>(x, W1, b1, W2, b2, out);
}